// Round 4
// baseline (430.717 us; speedup 1.0000x reference)
//
#include <hip/hip_runtime.h>
#include <hip/hip_bf16.h>
#include <stdint.h>

// Problem constants (from setup_inputs): B=8192, D_in=1024, H=2048
#define B_DIM 8192
#define D_IN  1024
#define H_DIM 2048
#define K_DIM (D_IN + H_DIM)   // 3072: A = [x | u], Wc = [win | wr]

#define CV_CONST  (1.0f - 1.0f/150.0f)   // (1-ALPHA_V)
#define CUV_CONST (10.0f/150.0f)         // ALPHA_V*M
#define CU_CONST  0.9f                   // (1-ALPHA_U)
#define AU_CONST  0.1f                   // ALPHA_U

typedef __attribute__((ext_vector_type(8))) short short8;   // 8 bf16 = 4 VGPRs
typedef __attribute__((ext_vector_type(4))) float floatx4;

__device__ __forceinline__ unsigned short f2bf(float f) {
    union { float f; unsigned u; } x; x.f = f;
    unsigned r = x.u + 0x7fffu + ((x.u >> 16) & 1u);
    return (unsigned short)(r >> 16);
}

// ---------------------------------------------------------------------------
// Single fused pack: x,u -> Abf[8192][3072]; win,wr -> Wbf[2048][3072], bf16 RNE.
// ---------------------------------------------------------------------------
#define N4_X   ((B_DIM * D_IN)  / 4)   // 2097152
#define N4_U   ((B_DIM * H_DIM) / 4)   // 4194304
#define N4_WIN ((H_DIM * D_IN)  / 4)   //  524288
#define N4_WR  ((H_DIM * H_DIM) / 4)   // 1048576
#define N4_TOT (N4_X + N4_U + N4_WIN + N4_WR)   // 7864320 (= 30720 * 256)

__global__ __launch_bounds__(256)
void pack_all(const float4* __restrict__ x, const float4* __restrict__ u,
              const float4* __restrict__ win, const float4* __restrict__ wr,
              unsigned short* __restrict__ Abf, unsigned short* __restrict__ Wbf) {
    int i = blockIdx.x * 256 + threadIdx.x;
    const float4* src; unsigned short* dst; int shift, mask, coloff;
    if (i < N4_X)                    { src = x;   dst = Abf; shift = 10; mask = 1023; coloff = 0;    }
    else if (i < N4_X + N4_U)        { i -= N4_X; src = u;   dst = Abf; shift = 11; mask = 2047; coloff = D_IN; }
    else if (i < N4_X + N4_U + N4_WIN){ i -= N4_X + N4_U; src = win; dst = Wbf; shift = 10; mask = 1023; coloff = 0; }
    else                             { i -= N4_X + N4_U + N4_WIN; src = wr; dst = Wbf; shift = 11; mask = 2047; coloff = D_IN; }
    int idx = i << 2;
    int r = idx >> shift;
    int c = idx & mask;
    float4 f = src[i];
    ushort4 o;
    o.x = f2bf(f.x); o.y = f2bf(f.y); o.z = f2bf(f.z); o.w = f2bf(f.w);
    *(ushort4*)(dst + (size_t)r * K_DIM + coloff + c) = o;
}

// ---------------------------------------------------------------------------
// 256x256-tile, 8-wave, BK=64, 4-phase/K-tile (R2 skeleton — empirically best).
// NEW: B operand loaded DIRECTLY from global (L2/L3-resident Wc) into a
// double-buffered register set, one tile ahead. Only A goes through LDS.
// LDS traffic per block-tile: 256 KB -> 160 KB (below the MFMA floor).
// VMEM issue order per tile t: [P0: Alo(t+1) x2][P1: B(t+1) x8][P2: Ahi(t+1) x2],
// pinned by asm memory clobbers so counted-vmcnt proofs hold:
//   VMCNT(4)  @P0: proves B(t)   (newer: Ahi(t)2 + Alo(t+1)2)
//   VMCNT(12) @P2: proves Ahi(t) (newer: Alo(t+1)2 + B(t+1)8 + Ahi(t+1)2)
//   VMCNT(10) @P3: proves Alo(t+1) (newer: B(t+1)8 + Ahi(t+1)2) -> BAR
// Cross-wave proofs (A units) are vmcnt -> BAR -> ds_read; B is wave-private.
// Fused epilogue: v_new = relu(cv*v + cuv*u); u_new = relu(cu*u + au*(gemm+b-v_new)).
// ---------------------------------------------------------------------------
#define GLOAD_LDS16(gp, lp)                                                          \
    __builtin_amdgcn_global_load_lds(                                                \
        (const __attribute__((address_space(1))) unsigned int*)(gp),                 \
        (__attribute__((address_space(3))) unsigned int*)(lp), 16, 0, 0)

#define VMCNT(n)  asm volatile("s_waitcnt vmcnt(" #n ")" ::: "memory")
#define LGKM0     asm volatile("s_waitcnt lgkmcnt(0)" ::: "memory")
#define CPIN      asm volatile("" ::: "memory")
#define SCHEDB    __builtin_amdgcn_sched_barrier(0)
#define BAR       __builtin_amdgcn_s_barrier()
#define PRIO1     __builtin_amdgcn_s_setprio(1)
#define PRIO0     __builtin_amdgcn_s_setprio(0)

#define NT (K_DIM / 64)        // 48 K-tiles

// LDS: 2 buffers x 64 KiB stride (A units only; B bypasses LDS).
//   A-lo (i-frags 0..3 of both M halves) : offset 0     (16 KB)
//   A-hi (i-frags 4..7 of both M halves) : offset 49152 (16 KB)
// Each unit = 16 slots x 1024 B; slot = one wave-fragment (lane -> lane*16B).
// Full 128 KiB kept allocated => 1 block/CU => 2 waves/SIMD => 256-VGPR budget.
#define ALO 0
#define AHI 49152

// Epilogue scratch (aliases K-loop LDS after final sync)
#define ES_STRIDE 68
#define ES_REGION (16 * ES_STRIDE)          // 1088 floats per region

__global__ __launch_bounds__(512, 2)
void gemm_fused(const unsigned short* __restrict__ A,   // [8192][3072] bf16
                const unsigned short* __restrict__ Wc,  // [2048][3072] bf16
                const float* __restrict__ u_in,         // [8192][2048]
                const float* __restrict__ v_in,         // [8192][2048]
                const float* __restrict__ bias,         // [2048]
                float* __restrict__ out)                // [u_new | v_new]
{
    __shared__ __align__(16) unsigned char smem[131072];

    const int tid  = threadIdx.x;
    const int wave = tid >> 6;       // 0..7
    const int lane = tid & 63;
    const int wrh  = wave >> 2;      // 0..1 : M half (128 rows)
    const int wc   = wave & 3;       // 0..3 : N quarter (64 cols)

    // XCD-chunked bijective swizzle (256 blocks, 256 % 8 == 0)
    const int bid   = blockIdx.x;
    const int wid   = ((bid & 7) << 5) | (bid >> 3);
    const int tileM = (wid >> 3) << 8;     // 0..31 * 256
    const int tileN = (wid & 7)  << 8;     // 0..7  * 256

    const int frow = lane & 15;
    const int g    = lane >> 4;

    // A staging (unchanged from R2): thread (wave,lane) feeds slot (r*8+wave).
    const unsigned short* Ag = A  + (size_t)(tileM + (wave >> 1) * 16 + frow) * K_DIM
                                  + (wave & 1) * 32 + g * 8;
    const size_t R128 = (size_t)128 * K_DIM;
    const size_t R64  = (size_t) 64 * K_DIM;

    // B direct-load base: frag (j,s) at tile t = Br + j*16*K_DIM + t*64 + s*32.
    // Lane layout matches MFMA B-operand: row = wc*64 + j*16 + frow, k-chunk = g*8.
    // 4 lanes (same frow, g=0..3) share each 64B line -> 16 fully-used lines/load.
    const unsigned short* Br = Wc + (size_t)(tileN + wc * 64 + frow) * K_DIM + g * 8;

    const int w1024 = wave << 10;

    // ds_read byte base: A frag (i,s) -> slot wrh*8 + i*2 + s.
    const int aRd = (wrh << 13) + (lane << 4);

    floatx4 acc[8][4] = {};
    short8 Ar[4][2];
    short8 Bb0[8], Bb1[8];     // B double buffer, statically indexed

#define RD_A(cb, unit, i2s) (*(const short8*)(smem + (cb) + (unit) + aRd + (i2s) * 1024))

    // ---- prologue: issue in steady-state order: Alo(0), B(0), Ahi(0)
    GLOAD_LDS16(Ag,        smem + ALO + w1024);
    GLOAD_LDS16(Ag + R128, smem + ALO + 8192 + w1024);
    CPIN;
#pragma unroll
    for (int j = 0; j < 4; ++j) {
        Bb0[j*2+0] = *(const short8*)(Br + (size_t)j * 16 * K_DIM);
        Bb0[j*2+1] = *(const short8*)(Br + (size_t)j * 16 * K_DIM + 32);
    }
    CPIN;
    GLOAD_LDS16(Ag + R64,        smem + AHI + w1024);
    GLOAD_LDS16(Ag + R64 + R128, smem + AHI + 8192 + w1024);
    VMCNT(10);   // proves Alo(0); leaves {B(0)8, Ahi(0)2}
    BAR; SCHEDB;

// One K-tile body. CB/NB = LDS buffer byte offsets; BCUR/BNXT = B reg buffers.
#define TILE_BODY(T, CB, NB, BCUR, BNXT)                                             \
    {                                                                                \
        const size_t kk = (size_t)((T) + 1) * 64;                                    \
        /* P0: stage next A-lo; read cur A-lo; prove B(t); MFMA lo x Bl */           \
        GLOAD_LDS16(Ag + kk,        smem + (NB) + ALO + w1024);                      \
        GLOAD_LDS16(Ag + kk + R128, smem + (NB) + ALO + 8192 + w1024);               \
        _Pragma("unroll")                                                            \
        for (int i = 0; i < 4; ++i) {                                                \
            Ar[i][0] = RD_A(CB, ALO, i*2); Ar[i][1] = RD_A(CB, ALO, i*2+1);          \
        }                                                                            \
        VMCNT(4); BAR; LGKM0; SCHEDB;                                                \
        PRIO1;                                                                       \
        _Pragma("unroll")                                                            \
        for (int i = 0; i < 4; ++i)                                                  \
            _Pragma("unroll")                                                        \
            for (int j = 0; j < 2; ++j) {                                            \
                acc[i][j] = __builtin_amdgcn_mfma_f32_16x16x32_bf16(Ar[i][0], BCUR[j*2+0], acc[i][j], 0, 0, 0); \
                acc[i][j] = __builtin_amdgcn_mfma_f32_16x16x32_bf16(Ar[i][1], BCUR[j*2+1], acc[i][j], 0, 0, 0); \
            }                                                                        \
        PRIO0; SCHEDB; BAR;                                                          \
        /* P1: issue B(t+1) to BNXT; MFMA lo x Bh */                                 \
        _Pragma("unroll")                                                            \
        for (int j = 0; j < 4; ++j) {                                                \
            BNXT[j*2+0] = *(const short8*)(Br + (size_t)j * 16 * K_DIM + kk);        \
            BNXT[j*2+1] = *(const short8*)(Br + (size_t)j * 16 * K_DIM + kk + 32);   \
        }                                                                            \
        CPIN;                                                                        \
        PRIO1;                                                                       \
        _Pragma("unroll")                                                            \
        for (int i = 0; i < 4; ++i)                                                  \
            _Pragma("unroll")                                                        \
            for (int j = 0; j < 2; ++j) {                                            \
                acc[i][2+j] = __builtin_amdgcn_mfma_f32_16x16x32_bf16(Ar[i][0], BCUR[4+j*2+0], acc[i][2+j], 0, 0, 0); \
                acc[i][2+j] = __builtin_amdgcn_mfma_f32_16x16x32_bf16(Ar[i][1], BCUR[4+j*2+1], acc[i][2+j], 0, 0, 0); \
            }                                                                        \
        PRIO0; SCHEDB; BAR;                                                          \
        /* P2: stage next A-hi; prove+read cur A-hi; MFMA hi x Bh */                 \
        GLOAD_LDS16(Ag + kk + R64,        smem + (NB) + AHI + w1024);                \
        GLOAD_LDS16(Ag + kk + R64 + R128, smem + (NB) + AHI + 8192 + w1024);         \
        VMCNT(12); BAR; SCHEDB;                                                      \
        _Pragma("unroll")                                                            \
        for (int i = 0; i < 4; ++i) {                                                \
            Ar[i][0] = RD_A(CB, AHI, i*2); Ar[i][1] = RD_A(CB, AHI, i*2+1);          \
        }                                                                            \
        LGKM0; SCHEDB;                                                               \
        PRIO1;                                                                       \
        _Pragma("unroll")                                                            \
        for (int i = 0; i < 4; ++i)                                                  \
            _Pragma("unroll")                                                        \
            for (int j = 0; j < 2; ++j) {                                            \
                acc[4+i][2+j] = __builtin_amdgcn_mfma_f32_16x16x32_bf16(Ar[i][0], BCUR[4+j*2+0], acc[4+i][2+j], 0, 0, 0); \
                acc[4+i][2+j] = __builtin_amdgcn_mfma_f32_16x16x32_bf16(Ar[i][1], BCUR[4+j*2+1], acc[4+i][2+j], 0, 0, 0); \
            }                                                                        \
        PRIO0; SCHEDB; BAR;                                                          \
        /* P3: MFMA hi x Bl; end-of-tile proof of Alo(t+1) + WAR barrier */          \
        PRIO1;                                                                       \
        _Pragma("unroll")                                                            \
        for (int i = 0; i < 4; ++i)                                                  \
            _Pragma("unroll")                                                        \
            for (int j = 0; j < 2; ++j) {                                            \
                acc[4+i][j] = __builtin_amdgcn_mfma_f32_16x16x32_bf16(Ar[i][0], BCUR[j*2+0], acc[4+i][j], 0, 0, 0); \
                acc[4+i][j] = __builtin_amdgcn_mfma_f32_16x16x32_bf16(Ar[i][1], BCUR[j*2+1], acc[4+i][j], 0, 0, 0); \
            }                                                                        \
        PRIO0; SCHEDB;                                                               \
        VMCNT(10); LGKM0; BAR;                                                       \
    }

    // 46 tiles as 23 even/odd pairs (static buffer names -> no dynamic reg idx)
    for (int tp = 0; tp < 23; ++tp) {
        const int t0 = tp * 2;
        TILE_BODY(t0,     0,     65536, Bb0, Bb1)
        TILE_BODY(t0 + 1, 65536, 0,     Bb1, Bb0)
    }
    TILE_BODY(46, 0, 65536, Bb0, Bb1)

    // ---- drain tile t = 47 (cb = 65536, B in Bb1; no staging)
    {
#pragma unroll
        for (int i = 0; i < 4; ++i) {
            Ar[i][0] = RD_A(65536, ALO, i*2); Ar[i][1] = RD_A(65536, ALO, i*2+1);
        }
        VMCNT(2); LGKM0; SCHEDB;   // proves B(47); leaves Ahi(47) in flight
        PRIO1;
#pragma unroll
        for (int i = 0; i < 4; ++i)
#pragma unroll
            for (int j = 0; j < 2; ++j) {
                acc[i][j]   = __builtin_amdgcn_mfma_f32_16x16x32_bf16(Ar[i][0], Bb1[j*2+0], acc[i][j],   0, 0, 0);
                acc[i][j]   = __builtin_amdgcn_mfma_f32_16x16x32_bf16(Ar[i][1], Bb1[j*2+1], acc[i][j],   0, 0, 0);
                acc[i][2+j] = __builtin_amdgcn_mfma_f32_16x16x32_bf16(Ar[i][0], Bb1[4+j*2+0], acc[i][2+j], 0, 0, 0);
                acc[i][2+j] = __builtin_amdgcn_mfma_f32_16x16x32_bf16(Ar[i][1], Bb1[4+j*2+1], acc[i][2+j], 0, 0, 0);
            }
        PRIO0; SCHEDB;
        VMCNT(0); BAR; SCHEDB;     // cross-wave proof of Ahi(47)
#pragma unroll
        for (int i = 0; i < 4; ++i) {
            Ar[i][0] = RD_A(65536, AHI, i*2); Ar[i][1] = RD_A(65536, AHI, i*2+1);
        }
        LGKM0; SCHEDB;
        PRIO1;
#pragma unroll
        for (int i = 0; i < 4; ++i)
#pragma unroll
            for (int j = 0; j < 2; ++j) {
                acc[4+i][2+j] = __builtin_amdgcn_mfma_f32_16x16x32_bf16(Ar[i][0], Bb1[4+j*2+0], acc[4+i][2+j], 0, 0, 0);
                acc[4+i][2+j] = __builtin_amdgcn_mfma_f32_16x16x32_bf16(Ar[i][1], Bb1[4+j*2+1], acc[4+i][2+j], 0, 0, 0);
                acc[4+i][j]   = __builtin_amdgcn_mfma_f32_16x16x32_bf16(Ar[i][0], Bb1[j*2+0], acc[4+i][j],   0, 0, 0);
                acc[4+i][j]   = __builtin_amdgcn_mfma_f32_16x16x32_bf16(Ar[i][1], Bb1[j*2+1], acc[4+i][j],   0, 0, 0);
            }
        PRIO0;
    }

    __syncthreads();   // end of pipeline: safe to alias LDS for epilogue

    // ---- epilogue: transpose each 16x64 i-slice through LDS, then float4 I/O.
    // C/D layout: col = lane&15 (output col), row = (lane>>4)*4 + reg.
    float* Esf = (float*)smem;
    const int q    = lane >> 4;        // 0..3
    const int c16  = lane & 15;
    const int colg = tileN + wc * 64 + c16 * 4;
    const float4 b4 = *(const float4*)&bias[colg];
    const size_t outV = (size_t)B_DIM * H_DIM;

#pragma unroll
    for (int i = 0; i < 8; ++i) {
        float* Es = Esf + (wave * 2 + (i & 1)) * ES_REGION;
        // stage acc slice i (b32 writes, 2 lanes/bank -> conflict-free)
#pragma unroll
        for (int j = 0; j < 4; ++j)
#pragma unroll
            for (int r = 0; r < 4; ++r)
                Es[(q * 4 + r) * ES_STRIDE + j * 16 + c16] = acc[i][j][r];
        // consume: 4 rows x 64 cols per pass, fully coalesced float4
#pragma unroll
        for (int rg = 0; rg < 4; rg++) {
            const int rloc = rg * 4 + q;
            const float4 a4 = *(const float4*)&Es[rloc * ES_STRIDE + c16 * 4];
            const size_t idx = (size_t)(tileM + wrh * 128 + i * 16 + rloc) * H_DIM + colg;
            const float4 u4 = *(const float4*)&u_in[idx];
            const float4 v4 = *(const float4*)&v_in[idx];
            float4 vn, un;
            vn.x = fmaxf(CV_CONST * v4.x + CUV_CONST * u4.x, 0.0f);
            vn.y = fmaxf(CV_CONST * v4.y + CUV_CONST * u4.y, 0.0f);
            vn.z = fmaxf(CV_CONST * v4.z + CUV_CONST * u4.z, 0.0f);
            vn.w = fmaxf(CV_CONST * v4.w + CUV_CONST * u4.w, 0.0f);
            un.x = fmaxf(CU_CONST * u4.x + AU_CONST * (a4.x + b4.x - vn.x), 0.0f);
            un.y = fmaxf(CU_CONST * u4.y + AU_CONST * (a4.y + b4.y - vn.y), 0.0f);
            un.z = fmaxf(CU_CONST * u4.z + AU_CONST * (a4.z + b4.z - vn.z), 0.0f);
            un.w = fmaxf(CU_CONST * u4.w + AU_CONST * (a4.w + b4.w - vn.w), 0.0f);
            *(float4*)&out[idx]        = un;
            *(float4*)&out[outV + idx] = vn;
        }
    }
}

// ---------------------------------------------------------------------------
extern "C" void kernel_launch(void* const* d_in, const int* in_sizes, int n_in,
                              void* d_out, int out_size, void* d_ws, size_t ws_size,
                              hipStream_t stream) {
    const float* x    = (const float*)d_in[0];
    const float* u    = (const float*)d_in[1];
    const float* v    = (const float*)d_in[2];
    const float* win  = (const float*)d_in[3];
    const float* wr   = (const float*)d_in[4];
    const float* bias = (const float*)d_in[5];
    float* out = (float*)d_out;

    unsigned short* Abf = (unsigned short*)d_ws;
    unsigned short* Wbf = Abf + (size_t)B_DIM * K_DIM;

    pack_all<<<N4_TOT / 256, 256, 0, stream>>>(
        (const float4*)x, (const float4*)u, (const float4*)win, (const float4*)wr,
        Abf, Wbf);

    gemm_fused<<<256, 512, 0, stream>>>(Abf, Wbf, u, v, bias, out);
}

// Round 5
// 377.303 us; speedup vs baseline: 1.1416x; 1.1416x over previous
//
#include <hip/hip_runtime.h>
#include <hip/hip_bf16.h>
#include <stdint.h>

// Problem constants (from setup_inputs): B=8192, D_in=1024, H=2048
#define B_DIM 8192
#define D_IN  1024
#define H_DIM 2048
#define K_DIM (D_IN + H_DIM)   // 3072: A = [x | u], Wc = [win | wr]

#define CV_CONST  (1.0f - 1.0f/150.0f)   // (1-ALPHA_V)
#define CUV_CONST (10.0f/150.0f)         // ALPHA_V*M
#define CU_CONST  0.9f                   // (1-ALPHA_U)
#define AU_CONST  0.1f                   // ALPHA_U

typedef __attribute__((ext_vector_type(8))) short short8;   // 8 bf16 = 4 VGPRs
typedef __attribute__((ext_vector_type(4))) float floatx4;

__device__ __forceinline__ unsigned short f2bf(float f) {
    union { float f; unsigned u; } x; x.f = f;
    unsigned r = x.u + 0x7fffu + ((x.u >> 16) & 1u);
    return (unsigned short)(r >> 16);
}

// ---------------------------------------------------------------------------
// Single fused pack: x,u -> Abf[8192][3072]; win,wr -> Wbf[2048][3072], bf16 RNE.
// ---------------------------------------------------------------------------
#define N4_X   ((B_DIM * D_IN)  / 4)   // 2097152
#define N4_U   ((B_DIM * H_DIM) / 4)   // 4194304
#define N4_WIN ((H_DIM * D_IN)  / 4)   //  524288
#define N4_WR  ((H_DIM * H_DIM) / 4)   // 1048576
#define N4_TOT (N4_X + N4_U + N4_WIN + N4_WR)   // 7864320 (= 30720 * 256)

__global__ __launch_bounds__(256)
void pack_all(const float4* __restrict__ x, const float4* __restrict__ u,
              const float4* __restrict__ win, const float4* __restrict__ wr,
              unsigned short* __restrict__ Abf, unsigned short* __restrict__ Wbf) {
    int i = blockIdx.x * 256 + threadIdx.x;
    const float4* src; unsigned short* dst; int shift, mask, coloff;
    if (i < N4_X)                    { src = x;   dst = Abf; shift = 10; mask = 1023; coloff = 0;    }
    else if (i < N4_X + N4_U)        { i -= N4_X; src = u;   dst = Abf; shift = 11; mask = 2047; coloff = D_IN; }
    else if (i < N4_X + N4_U + N4_WIN){ i -= N4_X + N4_U; src = win; dst = Wbf; shift = 10; mask = 1023; coloff = 0; }
    else                             { i -= N4_X + N4_U + N4_WIN; src = wr; dst = Wbf; shift = 11; mask = 2047; coloff = D_IN; }
    int idx = i << 2;
    int r = idx >> shift;
    int c = idx & mask;
    float4 f = src[i];
    ushort4 o;
    o.x = f2bf(f.x); o.y = f2bf(f.y); o.z = f2bf(f.z); o.w = f2bf(f.w);
    *(ushort4*)(dst + (size_t)r * K_DIM + coloff + c) = o;
}

// ---------------------------------------------------------------------------
// 256x256-tile, 8-wave, BK=64, full-tile double buffer. R5: LOW-SYNC K-loop —
// 2 barriers + 2 counted vmcnt + 3 counted lgkmcnt per tile (vs R2's 8 BAR +
// 3 vmcnt + 4 lgkm0). Counted lgkmcnt lets LDS serve run UNDER the MFMA
// clusters instead of fully serializing (R2's measured bottleneck).
//
// Units per tile: U1=Alo, U2=Blo, U3=Bhi, U4=Ahi (16 KB each, 2 gloads/wave).
// Tile-entry invariant: U1-U3(t) proven by t-1's VMCNT(2)->BAR; U4(t) proven
// by this tile's VMCNT(6)->BAR. Staging: U1-U3(t+1) at phase-A start, U4(t+1)
// mid-tile. Queue accounting (in-order, vmcnt-only for global_load_lds):
//   @A: outstanding = U4(t)2 + U1-U3(t+1)6 = 8 -> VMCNT(6) proves U4(t)
//   @B: outstanding = U1-U4(t+1)           = 8 -> VMCNT(2) proves U1-U3(t+1)
// WAR: all reads of cb retired at the last lgkmcnt(0) (before c3/c4), which
// precedes phase-B's BAR; t+1's staging into cb comes after that BAR.
// sched_barrier(0) after every counted lgkm wait (hipcc hoists reg-only MFMA
// past inline-asm waitcnt otherwise).
// Fragment-major linear LDS (1 KiB slot = one wave-frag, lane -> lane*16B,
// conflict-free ds_read_b128) fed by pre-permuted global sources.
// Fused epilogue: v_new = relu(cv*v + cuv*u); u_new = relu(cu*u + au*(gemm+b-v_new)).
// ---------------------------------------------------------------------------
#define GLOAD_LDS16(gp, lp)                                                          \
    __builtin_amdgcn_global_load_lds(                                                \
        (const __attribute__((address_space(1))) unsigned int*)(gp),                 \
        (__attribute__((address_space(3))) unsigned int*)(lp), 16, 0, 0)

#define VMCNT(n)  asm volatile("s_waitcnt vmcnt(" #n ")" ::: "memory")
#define LGKM(n)   asm volatile("s_waitcnt lgkmcnt(" #n ")" ::: "memory")
#define SCHEDB    __builtin_amdgcn_sched_barrier(0)
#define BAR       __builtin_amdgcn_s_barrier()
#define PRIO1     __builtin_amdgcn_s_setprio(1)
#define PRIO0     __builtin_amdgcn_s_setprio(0)

#define NT (K_DIM / 64)        // 48 K-tiles

// LDS: 2 buffers x 64 KiB. Unit byte offsets within a buffer:
//   A-lo (i-frags 0..3 of both M halves) : 0
//   B-lo (j-frags 0..1 of all wc)        : 16384
//   B-hi (j-frags 2..3 of all wc)        : 32768
//   A-hi (i-frags 4..7 of both M halves) : 49152
// Each unit = 16 slots x 1024 B; slot = one wave-fragment (lane -> lane*16B).
#define ALO 0
#define BLO 16384
#define BHI 32768
#define AHI 49152

// Epilogue scratch (aliases K-loop LDS after final sync)
#define ES_STRIDE 68
#define ES_REGION (16 * ES_STRIDE)          // 1088 floats per region

__global__ __launch_bounds__(512, 2)
void gemm_fused(const unsigned short* __restrict__ A,   // [8192][3072] bf16
                const unsigned short* __restrict__ Wc,  // [2048][3072] bf16
                const float* __restrict__ u_in,         // [8192][2048]
                const float* __restrict__ v_in,         // [8192][2048]
                const float* __restrict__ bias,         // [2048]
                float* __restrict__ out)                // [u_new | v_new]
{
    __shared__ __align__(16) unsigned char smem[131072];

    const int tid  = threadIdx.x;
    const int wave = tid >> 6;       // 0..7
    const int lane = tid & 63;
    const int wrh  = wave >> 2;      // 0..1 : M half (128 rows)
    const int wc   = wave & 3;       // 0..3 : N quarter (64 cols)

    // XCD-chunked bijective swizzle (256 blocks, 256 % 8 == 0)
    const int bid   = blockIdx.x;
    const int wid   = ((bid & 7) << 5) | (bid >> 3);
    const int tileM = (wid >> 3) << 8;     // 0..31 * 256
    const int tileN = (wid & 7)  << 8;     // 0..7  * 256

    const int frow = lane & 15;
    const int g    = lane >> 4;

    // Staging source pointers: thread (wave,lane) feeds slot (r*8+wave), lane l.
    const unsigned short* Ag = A  + (size_t)(tileM + (wave >> 1) * 16 + frow) * K_DIM
                                  + (wave & 1) * 32 + g * 8;
    const unsigned short* Bg = Wc + (size_t)(tileN + (wave >> 2) * 64 + ((wave >> 1) & 1) * 16 + frow) * K_DIM
                                  + (wave & 1) * 32 + g * 8;
    const size_t R128 = (size_t)128 * K_DIM;
    const size_t R64  = (size_t) 64 * K_DIM;
    const size_t R32  = (size_t) 32 * K_DIM;

    const int w1024 = wave << 10;

    // ds_read byte bases (within a buffer): A frag (i,s) -> slot wrh*8 + i*2 + s;
    //                                       B frag (j,s) -> slot wc*4 + j*2 + s.
    const int aRd = (wrh << 13) + (lane << 4);
    const int bRd = (wc  << 12) + (lane << 4);

    // ---- prologue: stage tile 0 into buffer 0 (order U1,U2,U3,U4)
    GLOAD_LDS16(Ag,               smem + ALO + w1024);
    GLOAD_LDS16(Ag + R128,        smem + ALO + 8192 + w1024);
    GLOAD_LDS16(Bg,               smem + BLO + w1024);
    GLOAD_LDS16(Bg + R128,        smem + BLO + 8192 + w1024);
    GLOAD_LDS16(Bg + R32,         smem + BHI + w1024);
    GLOAD_LDS16(Bg + R32 + R128,  smem + BHI + 8192 + w1024);
    GLOAD_LDS16(Ag + R64,         smem + AHI + w1024);
    GLOAD_LDS16(Ag + R64 + R128,  smem + AHI + 8192 + w1024);
    VMCNT(2);    // proves U1-U3(0); U4(0) stays in flight (steady-state entry)
    BAR;

    floatx4 acc[8][4] = {};
    short8 Ar[4][2], Bl[2][2], Bh[2][2];

#define RD_A(cb, unit, i2s) (*(const short8*)(smem + (cb) + (unit) + aRd + (i2s) * 1024))
#define RD_B(cb, unit, j2s) (*(const short8*)(smem + (cb) + (unit) + bRd + (j2s) * 1024))

#pragma clang loop unroll(disable)
    for (int t = 0; t < NT - 1; ++t) {
        const int cb = (t & 1) << 16;
        const int nb = cb ^ 65536;
        const size_t kk = (size_t)(t + 1) * 64;

        // ---- Phase A: stage U1-U3(t+1) into nb (nb's old units retired last
        // tile); pre-barrier reads of proven units U1-U3(t); prove U4(t).
        GLOAD_LDS16(Ag + kk,              smem + nb + ALO + w1024);
        GLOAD_LDS16(Ag + kk + R128,       smem + nb + ALO + 8192 + w1024);
        GLOAD_LDS16(Bg + kk,              smem + nb + BLO + w1024);
        GLOAD_LDS16(Bg + kk + R128,       smem + nb + BLO + 8192 + w1024);
        GLOAD_LDS16(Bg + kk + R32,        smem + nb + BHI + w1024);
        GLOAD_LDS16(Bg + kk + R32 + R128, smem + nb + BHI + 8192 + w1024);

        // reads (issue order matters for counted lgkm): Bl(4), Alo(8), Bh(4)
#pragma unroll
        for (int j = 0; j < 2; ++j) { Bl[j][0] = RD_B(cb, BLO, j*2); Bl[j][1] = RD_B(cb, BLO, j*2+1); }
#pragma unroll
        for (int i = 0; i < 4; ++i) { Ar[i][0] = RD_A(cb, ALO, i*2); Ar[i][1] = RD_A(cb, ALO, i*2+1); }
#pragma unroll
        for (int j = 0; j < 2; ++j) { Bh[j][0] = RD_B(cb, BHI, j*2); Bh[j][1] = RD_B(cb, BHI, j*2+1); }

        VMCNT(6);        // outstanding: U4(t)2 + U1-U3(t+1)6 -> proves U4(t)
        BAR;             // all waves proved U4(t); serve of reads ran under wait
        SCHEDB;

        // c1: lo x Bl — needs first 12 reads (Bl+Alo); Bh(4) may still serve
        LGKM(4); SCHEDB;
        PRIO1;
#pragma unroll
        for (int i = 0; i < 4; ++i)
#pragma unroll
            for (int j = 0; j < 2; ++j) {
                acc[i][j] = __builtin_amdgcn_mfma_f32_16x16x32_bf16(Ar[i][0], Bl[j][0], acc[i][j], 0, 0, 0);
                acc[i][j] = __builtin_amdgcn_mfma_f32_16x16x32_bf16(Ar[i][1], Bl[j][1], acc[i][j], 0, 0, 0);
            }
        PRIO0;

        // c2: lo x Bh
        LGKM(0); SCHEDB;
        PRIO1;
#pragma unroll
        for (int i = 0; i < 4; ++i)
#pragma unroll
            for (int j = 0; j < 2; ++j) {
                acc[i][2+j] = __builtin_amdgcn_mfma_f32_16x16x32_bf16(Ar[i][0], Bh[j][0], acc[i][2+j], 0, 0, 0);
                acc[i][2+j] = __builtin_amdgcn_mfma_f32_16x16x32_bf16(Ar[i][1], Bh[j][1], acc[i][2+j], 0, 0, 0);
            }
        PRIO0;

        // mid: stage U4(t+1); read Ahi(t) into Ar (proven at this tile's BAR)
        GLOAD_LDS16(Ag + kk + R64,        smem + nb + AHI + w1024);
        GLOAD_LDS16(Ag + kk + R64 + R128, smem + nb + AHI + 8192 + w1024);
#pragma unroll
        for (int i = 0; i < 4; ++i) { Ar[i][0] = RD_A(cb, AHI, i*2); Ar[i][1] = RD_A(cb, AHI, i*2+1); }

        // c3 + c4: hi x Bh, hi x Bl
        LGKM(0); SCHEDB;
        PRIO1;
#pragma unroll
        for (int i = 0; i < 4; ++i)
#pragma unroll
            for (int j = 0; j < 2; ++j) {
                acc[4+i][2+j] = __builtin_amdgcn_mfma_f32_16x16x32_bf16(Ar[i][0], Bh[j][0], acc[4+i][2+j], 0, 0, 0);
                acc[4+i][2+j] = __builtin_amdgcn_mfma_f32_16x16x32_bf16(Ar[i][1], Bh[j][1], acc[4+i][2+j], 0, 0, 0);
            }
#pragma unroll
        for (int i = 0; i < 4; ++i)
#pragma unroll
            for (int j = 0; j < 2; ++j) {
                acc[4+i][j] = __builtin_amdgcn_mfma_f32_16x16x32_bf16(Ar[i][0], Bl[j][0], acc[4+i][j], 0, 0, 0);
                acc[4+i][j] = __builtin_amdgcn_mfma_f32_16x16x32_bf16(Ar[i][1], Bl[j][1], acc[4+i][j], 0, 0, 0);
            }
        PRIO0;

        // ---- Phase B: prove U1-U3(t+1) for next tile; WAR-release cb (all my
        // reads retired at the LGKM(0) above).
        VMCNT(2);
        BAR;
    }

    // ---- drain tile t = NT-1 (cb = 65536; no staging)
    {
        const int cb = ((NT - 1) & 1) << 16;
#pragma unroll
        for (int j = 0; j < 2; ++j) { Bl[j][0] = RD_B(cb, BLO, j*2); Bl[j][1] = RD_B(cb, BLO, j*2+1); }
#pragma unroll
        for (int i = 0; i < 4; ++i) { Ar[i][0] = RD_A(cb, ALO, i*2); Ar[i][1] = RD_A(cb, ALO, i*2+1); }
#pragma unroll
        for (int j = 0; j < 2; ++j) { Bh[j][0] = RD_B(cb, BHI, j*2); Bh[j][1] = RD_B(cb, BHI, j*2+1); }
        VMCNT(0);        // proves U4(last); queue empty
        BAR;
        SCHEDB;
        LGKM(4); SCHEDB;
        PRIO1;
#pragma unroll
        for (int i = 0; i < 4; ++i)
#pragma unroll
            for (int j = 0; j < 2; ++j) {
                acc[i][j] = __builtin_amdgcn_mfma_f32_16x16x32_bf16(Ar[i][0], Bl[j][0], acc[i][j], 0, 0, 0);
                acc[i][j] = __builtin_amdgcn_mfma_f32_16x16x32_bf16(Ar[i][1], Bl[j][1], acc[i][j], 0, 0, 0);
            }
        PRIO0;
        LGKM(0); SCHEDB;
        PRIO1;
#pragma unroll
        for (int i = 0; i < 4; ++i)
#pragma unroll
            for (int j = 0; j < 2; ++j) {
                acc[i][2+j] = __builtin_amdgcn_mfma_f32_16x16x32_bf16(Ar[i][0], Bh[j][0], acc[i][2+j], 0, 0, 0);
                acc[i][2+j] = __builtin_amdgcn_mfma_f32_16x16x32_bf16(Ar[i][1], Bh[j][1], acc[i][2+j], 0, 0, 0);
            }
        PRIO0;
#pragma unroll
        for (int i = 0; i < 4; ++i) { Ar[i][0] = RD_A(cb, AHI, i*2); Ar[i][1] = RD_A(cb, AHI, i*2+1); }
        LGKM(0); SCHEDB;
        PRIO1;
#pragma unroll
        for (int i = 0; i < 4; ++i)
#pragma unroll
            for (int j = 0; j < 2; ++j) {
                acc[4+i][2+j] = __builtin_amdgcn_mfma_f32_16x16x32_bf16(Ar[i][0], Bh[j][0], acc[4+i][2+j], 0, 0, 0);
                acc[4+i][2+j] = __builtin_amdgcn_mfma_f32_16x16x32_bf16(Ar[i][1], Bh[j][1], acc[4+i][2+j], 0, 0, 0);
                acc[4+i][j]   = __builtin_amdgcn_mfma_f32_16x16x32_bf16(Ar[i][0], Bl[j][0], acc[4+i][j],   0, 0, 0);
                acc[4+i][j]   = __builtin_amdgcn_mfma_f32_16x16x32_bf16(Ar[i][1], Bl[j][1], acc[4+i][j],   0, 0, 0);
            }
        PRIO0;
    }

    __syncthreads();   // end of pipeline: safe to alias LDS for epilogue

    // ---- epilogue: transpose each 16x64 i-slice through LDS, then float4 I/O.
    // C/D layout: col = lane&15 (output col), row = (lane>>4)*4 + reg.
    float* Esf = (float*)smem;
    const int q    = lane >> 4;        // 0..3
    const int c16  = lane & 15;
    const int colg = tileN + wc * 64 + c16 * 4;
    const float4 b4 = *(const float4*)&bias[colg];
    const size_t outV = (size_t)B_DIM * H_DIM;

#pragma unroll
    for (int i = 0; i < 8; ++i) {
        float* Es = Esf + (wave * 2 + (i & 1)) * ES_REGION;
        // stage acc slice i (b32 writes, 2 lanes/bank -> conflict-free)
#pragma unroll
        for (int j = 0; j < 4; ++j)
#pragma unroll
            for (int r = 0; r < 4; ++r)
                Es[(q * 4 + r) * ES_STRIDE + j * 16 + c16] = acc[i][j][r];
        // consume: 4 rows x 64 cols per pass, fully coalesced float4
#pragma unroll
        for (int rg = 0; rg < 4; rg++) {
            const int rloc = rg * 4 + q;
            const float4 a4 = *(const float4*)&Es[rloc * ES_STRIDE + c16 * 4];
            const size_t idx = (size_t)(tileM + wrh * 128 + i * 16 + rloc) * H_DIM + colg;
            const float4 u4 = *(const float4*)&u_in[idx];
            const float4 v4 = *(const float4*)&v_in[idx];
            float4 vn, un;
            vn.x = fmaxf(CV_CONST * v4.x + CUV_CONST * u4.x, 0.0f);
            vn.y = fmaxf(CV_CONST * v4.y + CUV_CONST * u4.y, 0.0f);
            vn.z = fmaxf(CV_CONST * v4.z + CUV_CONST * u4.z, 0.0f);
            vn.w = fmaxf(CV_CONST * v4.w + CUV_CONST * u4.w, 0.0f);
            un.x = fmaxf(CU_CONST * u4.x + AU_CONST * (a4.x + b4.x - vn.x), 0.0f);
            un.y = fmaxf(CU_CONST * u4.y + AU_CONST * (a4.y + b4.y - vn.y), 0.0f);
            un.z = fmaxf(CU_CONST * u4.z + AU_CONST * (a4.z + b4.z - vn.z), 0.0f);
            un.w = fmaxf(CU_CONST * u4.w + AU_CONST * (a4.w + b4.w - vn.w), 0.0f);
            *(float4*)&out[idx]        = un;
            *(float4*)&out[outV + idx] = vn;
        }
    }
}

// ---------------------------------------------------------------------------
extern "C" void kernel_launch(void* const* d_in, const int* in_sizes, int n_in,
                              void* d_out, int out_size, void* d_ws, size_t ws_size,
                              hipStream_t stream) {
    const float* x    = (const float*)d_in[0];
    const float* u    = (const float*)d_in[1];
    const float* v    = (const float*)d_in[2];
    const float* win  = (const float*)d_in[3];
    const float* wr   = (const float*)d_in[4];
    const float* bias = (const float*)d_in[5];
    float* out = (float*)d_out;

    unsigned short* Abf = (unsigned short*)d_ws;
    unsigned short* Wbf = Abf + (size_t)B_DIM * K_DIM;

    pack_all<<<N4_TOT / 256, 256, 0, stream>>>(
        (const float4*)x, (const float4*)u, (const float4*)win, (const float4*)wr,
        Abf, Wbf);

    gemm_fused<<<256, 512, 0, stream>>>(Abf, Wbf, u, v, bias, out);
}